// Round 10
// baseline (227.113 us; speedup 1.0000x reference)
//
#include <hip/hip_runtime.h>

typedef __bf16 bf8 __attribute__((ext_vector_type(8)));
typedef float f4 __attribute__((ext_vector_type(4)));
typedef unsigned short us4 __attribute__((ext_vector_type(4)));
typedef unsigned int u32x4 __attribute__((ext_vector_type(4)));

#define MFMA16(a,b,c) __builtin_amdgcn_mfma_f32_16x16x32_bf16((a),(b),(c),0,0,0)

#define BLOCK 256
#define NWAVE 4

__device__ __forceinline__ unsigned short f2bfu(float f){
  __bf16 h = (__bf16)f;
  union { __bf16 b; unsigned short u; } v; v.b = h; return v.u;
}
__device__ __forceinline__ float ubfu(unsigned int u16){
  union { unsigned int i; float f; } v; v.i = u16 << 16; return v.f;
}

// Wave-local LDS fence (validated rounds 4-9, absmax 0.0).
__device__ __forceinline__ void wfence(){
  asm volatile("s_waitcnt lgkmcnt(0)" ::: "memory");
}

// LDS layout for MLP kernels (ushort element offsets)
#define OFF_W1   0
#define OFF_W2   2048
#define OFF_W3   6144
#define OFF_CW1  7168    // compact: k<16 half only
#define OFF_CW2  8192
#define OFF_CW3  12288
#define OFF_CW4  16384
#define OFF_ACT  17408
#define ACT_STRIDE 72
#define SMEM_US  (17408 + NWAVE*16*ACT_STRIDE)   // 22016 shorts = 44032 B -> 3 blocks/CU

#define BO_B1  0
#define BO_B2  64
#define BO_B3  128
#define BO_CB1 144
#define BO_CB2 208
#define BO_CB3 272
#define BO_CB4 336

template<int FIN,int FOUT,int KS,int MT>
__device__ __forceinline__ void stage_w(const float* w, unsigned short* dst){
  const int total = KS*MT*512;
  for (int e = threadIdx.x; e < total; e += BLOCK){
    int chunk = e >> 9;
    int s = chunk / MT, t = chunk % MT;
    int le = e & 511;
    int lane = le >> 3, j = le & 7;
    int q = lane >> 4, m = lane & 15;
    int i = s*32 + q*8 + j;
    int o = t*16 + m;
    dst[e] = (i < FIN && o < FOUT) ? f2bfu(w[i*FOUT + o]) : (unsigned short)0;
  }
}

__device__ __forceinline__ void stage_cw1(const float* w, unsigned short* dst){
  for (int e = threadIdx.x; e < 1024; e += BLOCK){
    int t = e >> 8;
    int le = e & 255;
    int lane = le >> 3, j = e & 7;
    int q = lane >> 4, m = lane & 15;
    dst[e] = f2bfu(w[(q*8+j)*64 + t*16 + m]);
  }
}

// 64->64 layer with REGISTER-resident weight fragments (wf[s*4+t]).
// Removes 8 ds_read_b128 per call vs the LDS variant — the round-9 profile
// showed the DS pipe (~820 cyc/iter) as the mlp bottleneck.
__device__ __forceinline__ void layer64_r(const bf8* wf, const unsigned short* bias,
                                          unsigned short* act, int lane, bool relu){
  const int q = lane >> 4, m = lane & 15;
  bf8 b0 = *(const bf8*)(act + m*ACT_STRIDE + q*8);
  bf8 b1 = *(const bf8*)(act + m*ACT_STRIDE + 32 + q*8);
  f4 acc[4];
#pragma unroll
  for (int t = 0; t < 4; ++t){
    f4 c = {0.f,0.f,0.f,0.f};
    c = MFMA16(wf[t], b0, c);
    c = MFMA16(wf[4+t], b1, c);
    acc[t] = c;
  }
#pragma unroll
  for (int t = 0; t < 4; ++t){
    us4 bb = *(const us4*)(bias + t*16 + q*4);
    us4 pk;
#pragma unroll
    for (int r = 0; r < 4; ++r){
      float v = acc[t][r] + ubfu(bb[r]);
      if (relu) v = fmaxf(v, 0.f);
      pk[r] = f2bfu(v);
    }
    *(us4*)(act + m*ACT_STRIDE + t*16 + q*4) = pk;
  }
}

#define STAGE_ALL_WEIGHTS()                                                  \
  stage_w<32,64,1,4>(w1,  smem+OFF_W1);                                      \
  stage_w<64,64,2,4>(w2,  smem+OFF_W2);                                      \
  stage_w<64,16,2,1>(w3,  smem+OFF_W3);                                      \
  stage_cw1(cw1, smem+OFF_CW1);                                              \
  stage_w<64,64,2,4>(cw2, smem+OFF_CW2);                                     \
  stage_w<64,64,2,4>(cw3, smem+OFF_CW3);                                     \
  stage_w<64, 3,2,1>(cw4, smem+OFF_CW4);                                     \
  {                                                                          \
    int t = threadIdx.x;                                                     \
    if (t < 64){                                                             \
      sbias[BO_B1 +t] = f2bfu(b1[t]);                                        \
      sbias[BO_B2 +t] = f2bfu(b2[t]);                                        \
      sbias[BO_CB1+t] = f2bfu(cb1[t]);                                       \
      sbias[BO_CB2+t] = f2bfu(cb2[t]);                                       \
      sbias[BO_CB3+t] = f2bfu(cb3[t]);                                       \
    }                                                                        \
    if (t < 16) sbias[BO_B3+t] = f2bfu(b3[t]);                               \
    if (t < 3)  sbias[BO_CB4+t] = f2bfu(cb4[t]);                             \
  }

// Hoist the three 64->64 weight sets into registers (96 VGPRs).
#define HOIST_W64()                                                          \
  bf8 w2f[8], cw2f[8], cw3f[8];                                              \
  _Pragma("unroll")                                                          \
  for (int s = 0; s < 8; ++s){                                               \
    w2f[s]  = *(const bf8*)(smem + OFF_W2  + (s*64+lane)*8);                 \
    cw2f[s] = *(const bf8*)(smem + OFF_CW2 + (s*64+lane)*8);                 \
    cw3f[s] = *(const bf8*)(smem + OFF_CW3 + (s*64+lane)*8);                 \
  }

// The MLP body for one iteration, starting from bfrag. Uses w2f/cw2f/cw3f
// register fragments from the enclosing scope.
#define MLP_BODY(bfrag, gp)                                                  \
    {                                                                        \
      f4 acc[4];                                                             \
      _Pragma("unroll")                                                      \
      for (int t = 0; t < 4; ++t){                                           \
        f4 c = {0.f,0.f,0.f,0.f};                                            \
        acc[t] = MFMA16(*(const bf8*)(smem + OFF_W1 + (t*64+lane)*8), bfrag, c);\
      }                                                                      \
      _Pragma("unroll")                                                      \
      for (int t = 0; t < 4; ++t){                                           \
        us4 bb = *(const us4*)(sbias + BO_B1 + t*16 + q*4);                  \
        us4 pk;                                                              \
        _Pragma("unroll")                                                    \
        for (int r = 0; r < 4; ++r){                                         \
          float v = fmaxf(acc[t][r] + ubfu(bb[r]), 0.f);                     \
          pk[r] = f2bfu(v);                                                  \
        }                                                                    \
        *(us4*)(act + m*ACT_STRIDE + t*16 + q*4) = pk;                       \
      }                                                                      \
    }                                                                        \
    wfence();                                                                \
    layer64_r(w2f, sbias+BO_B2, act, lane, true);                            \
    wfence();                                                                \
    {                                                                        \
      bf8 b0 = *(const bf8*)(act + m*ACT_STRIDE + q*8);                      \
      bf8 b1 = *(const bf8*)(act + m*ACT_STRIDE + 32 + q*8);                 \
      f4 c = {0.f,0.f,0.f,0.f};                                              \
      c = MFMA16(*(const bf8*)(smem + OFF_W3 + lane*8), b0, c);              \
      c = MFMA16(*(const bf8*)(smem + OFF_W3 + (64+lane)*8), b1, c);         \
      us4 bb = *(const us4*)(sbias + BO_B3 + q*4);                           \
      us4 pk;                                                                \
      float d0 = 0.f;                                                        \
      _Pragma("unroll")                                                      \
      for (int r = 0; r < 4; ++r){                                           \
        float v = c[r] + ubfu(bb[r]);                                        \
        if (r == 0) d0 = v;                                                  \
        pk[r] = f2bfu(v);                                                    \
      }                                                                      \
      if (q == 0 && gp < nB) out[gp] = expf(d0);                             \
      *(us4*)(act + m*ACT_STRIDE + q*4) = pk;                                \
    }                                                                        \
    wfence();                                                                \
    {                                                                        \
      bf8 bc, aw[4];                                                         \
      if (q < 2){                                                            \
        bc = *(const bf8*)(act + m*ACT_STRIDE + q*8);                        \
        _Pragma("unroll")                                                    \
        for (int t = 0; t < 4; ++t)                                          \
          aw[t] = *(const bf8*)(smem + OFF_CW1 + (t*32+lane)*8);             \
      } else {                                                               \
        _Pragma("unroll")                                                    \
        for (int j = 0; j < 8; ++j) bc[j] = (__bf16)0.f;                     \
        _Pragma("unroll")                                                    \
        for (int t = 0; t < 4; ++t) aw[t] = bc;                              \
      }                                                                      \
      f4 acc[4];                                                             \
      _Pragma("unroll")                                                      \
      for (int t = 0; t < 4; ++t){                                           \
        f4 c = {0.f,0.f,0.f,0.f};                                            \
        acc[t] = MFMA16(aw[t], bc, c);                                       \
      }                                                                      \
      _Pragma("unroll")                                                      \
      for (int t = 0; t < 4; ++t){                                           \
        us4 bb = *(const us4*)(sbias + BO_CB1 + t*16 + q*4);                 \
        us4 pk;                                                              \
        _Pragma("unroll")                                                    \
        for (int r = 0; r < 4; ++r){                                         \
          float v = fmaxf(acc[t][r] + ubfu(bb[r]), 0.f);                     \
          pk[r] = f2bfu(v);                                                  \
        }                                                                    \
        *(us4*)(act + m*ACT_STRIDE + t*16 + q*4) = pk;                       \
      }                                                                      \
    }                                                                        \
    wfence();                                                                \
    layer64_r(cw2f, sbias+BO_CB2, act, lane, true);                          \
    wfence();                                                                \
    layer64_r(cw3f, sbias+BO_CB3, act, lane, true);                          \
    wfence();                                                                \
    {                                                                        \
      bf8 b0 = *(const bf8*)(act + m*ACT_STRIDE + q*8);                      \
      bf8 b1 = *(const bf8*)(act + m*ACT_STRIDE + 32 + q*8);                 \
      f4 c = {0.f,0.f,0.f,0.f};                                              \
      c = MFMA16(*(const bf8*)(smem + OFF_CW4 + lane*8), b0, c);             \
      c = MFMA16(*(const bf8*)(smem + OFF_CW4 + (64+lane)*8), b1, c);        \
      if (q == 0 && gp < nB){                                                \
        _Pragma("unroll")                                                    \
        for (int r = 0; r < 3; ++r){                                         \
          float v = c[r] + ubfu(sbias[BO_CB4 + r]);                          \
          out[nB + gp*3 + r] = 1.f/(1.f + expf(-v));                         \
        }                                                                    \
      }                                                                      \
    }                                                                        \
    wfence();

// ---------------------------------------------------------------------------
// Phase A: per-level hash encode with the level's FULL table in LDS (bf16x2
// packed, 64 KB). 4B LDS gathers instead of 64B L2 lines. (unchanged, r9)
// ---------------------------------------------------------------------------
#define CH 16384
__global__ __launch_bounds__(512) void hash_phase(
    const float* __restrict__ xin, const float* __restrict__ tab,
    unsigned int* __restrict__ feat, int nB)
{
  __shared__ unsigned int stab[16384];
  __shared__ int sres[16];
  const int lvl = blockIdx.y;
  {
    const float2* t2 = (const float2*)tab + (lvl<<14);
    for (int e = threadIdx.x; e < 16384; e += 512){
      float2 v = t2[e];
      stab[e] = ((unsigned)f2bfu(v.y) << 16) | (unsigned)f2bfu(v.x);
    }
    if (threadIdx.x < 16){
      const int R[16] = {16,20,25,32,40,50,64,80,101,128,161,203,256,322,406,512};
      sres[threadIdx.x] = R[threadIdx.x];
    }
  }
  __syncthreads();

  const int res = sres[lvl];
  const float sc = 0.5f*(float)(res-1);
  const bool dense = (lvl < 3);
  unsigned int* fout = feat + (size_t)lvl * (size_t)nB;

  int pend = (blockIdx.x + 1) * CH; if (pend > nB) pend = nB;
  for (int p = blockIdx.x*CH + threadIdx.x; p < pend; p += 512){
    const float px = xin[p*3+0], py = xin[p*3+1], pz = xin[p*3+2];
    const float xs=(px+1.f)*sc, ys=(py+1.f)*sc, zs=(pz+1.f)*sc;
    const float fx=floorf(xs), fy=floorf(ys), fz=floorf(zs);
    const float wx=xs-fx, wy=ys-fy, wz=zs-fz;
    int ix0=min(max((int)fx,0),res-1);
    int iy0=min(max((int)fy,0),res-1);
    int iz0=min(max((int)fz,0),res-1);
    int ix1=min(ix0+1,res-1), iy1=min(iy0+1,res-1), iz1=min(iz0+1,res-1);
    unsigned X0,X1,Y0,Y1,Z0,Z1;
    if (dense){
      X0=(unsigned)ix0;            X1=(unsigned)ix1;
      Y0=(unsigned)(res*iy0);      Y1=(unsigned)(res*iy1);
      Z0=(unsigned)(res*res*iz0);  Z1=(unsigned)(res*res*iz1);
    } else {
      X0=(unsigned)ix0;                 X1=(unsigned)ix1;
      Y0=(unsigned)iy0*2654435761u;     Y1=(unsigned)iy1*2654435761u;
      Z0=(unsigned)iz0*805459861u;      Z1=(unsigned)iz1*805459861u;
    }
    const float wx0=1.f-wx, wy0=1.f-wy, wz0=1.f-wz;
    float f0=0.f, f1=0.f;
#pragma unroll
    for (int c = 0; c < 8; ++c){
      unsigned xc = (c&1)?X1:X0;
      unsigned yc = (c&2)?Y1:Y0;
      unsigned zc = (c&4)?Z1:Z0;
      unsigned idx = dense ? (xc+yc+zc) : ((xc^yc^zc)&16383u);
      unsigned tv = stab[idx];
      float wc = ((c&1)?wx:wx0) * ((c&2)?wy:wy0) * ((c&4)?wz:wz0);
      f0 += wc*ubfu(tv << 16);
      f1 += wc*ubfu(tv & 0xffff0000u);
    }
    fout[p] = ((unsigned)f2bfu(f1) << 16) | (unsigned)f2bfu(f0);
  }
}

// ---------------------------------------------------------------------------
// Phase B: MLP over precomputed features.
// ---------------------------------------------------------------------------
__global__ __launch_bounds__(BLOCK) void mlp_phase(
    const unsigned int* __restrict__ feat,
    const float* __restrict__ w1,  const float* __restrict__ b1,
    const float* __restrict__ w2,  const float* __restrict__ b2,
    const float* __restrict__ w3,  const float* __restrict__ b3,
    const float* __restrict__ cw1, const float* __restrict__ cb1,
    const float* __restrict__ cw2, const float* __restrict__ cb2,
    const float* __restrict__ cw3, const float* __restrict__ cb3,
    const float* __restrict__ cw4, const float* __restrict__ cb4,
    float* __restrict__ out, int nB)
{
  __shared__ __align__(16) unsigned short smem[SMEM_US];
  __shared__ __align__(16) unsigned short sbias[344];
  STAGE_ALL_WEIGHTS();
  __syncthreads();

  const int lane = threadIdx.x & 63, wv = threadIdx.x >> 6;
  const int q = lane >> 4, m = lane & 15;
  unsigned short* act = smem + OFF_ACT + wv*16*ACT_STRIDE;
  const unsigned int* fq = feat + (size_t)(4*q) * (size_t)nB;

  HOIST_W64();

  for (int it = 0; it < 4; ++it){
    const int gp  = blockIdx.x*BLOCK + wv*64 + it*16 + m;
    const int gpl = min(gp, nB-1);
    union { u32x4 u; bf8 b; } fb;
    fb.u[0] = fq[gpl];
    fb.u[1] = fq[(size_t)nB   + gpl];
    fb.u[2] = fq[(size_t)nB*2 + gpl];
    fb.u[3] = fq[(size_t)nB*3 + gpl];
    bf8 bfrag = fb.b;
    MLP_BODY(bfrag, gp)
  }
}

// ---------------------------------------------------------------------------
// Fallback: fused kernel (used only if workspace too small).
// ---------------------------------------------------------------------------
__global__ __launch_bounds__(BLOCK) void nerf_fused(
    const float* __restrict__ xin, const float* __restrict__ tab,
    const float* __restrict__ w1,  const float* __restrict__ b1,
    const float* __restrict__ w2,  const float* __restrict__ b2,
    const float* __restrict__ w3,  const float* __restrict__ b3,
    const float* __restrict__ cw1, const float* __restrict__ cb1,
    const float* __restrict__ cw2, const float* __restrict__ cb2,
    const float* __restrict__ cw3, const float* __restrict__ cb3,
    const float* __restrict__ cw4, const float* __restrict__ cb4,
    float* __restrict__ out, int nB)
{
  __shared__ __align__(16) unsigned short smem[SMEM_US];
  __shared__ __align__(16) unsigned short sbias[344];
  __shared__ int sres[16];
  STAGE_ALL_WEIGHTS();
  if (threadIdx.x < 16){
    const int R[16] = {16,20,25,32,40,50,64,80,101,128,161,203,256,322,406,512};
    sres[threadIdx.x] = R[threadIdx.x];
  }
  __syncthreads();

  const int lane = threadIdx.x & 63, wv = threadIdx.x >> 6;
  const int q = lane >> 4, m = lane & 15;
  unsigned short* act = smem + OFF_ACT + wv*16*ACT_STRIDE;

  HOIST_W64();

  int res_[4];
#pragma unroll
  for (int d = 0; d < 4; ++d) res_[d] = sres[4*q + d];

  for (int it = 0; it < 4; ++it){
    const int gp  = blockIdx.x*BLOCK + wv*64 + it*16 + m;
    const int gpl = min(gp, nB-1);
    const float px = xin[gpl*3+0];
    const float py = xin[gpl*3+1];
    const float pz = xin[gpl*3+2];

    bf8 bfrag;
#pragma unroll
    for (int d = 0; d < 4; ++d){
      const int lvl = 4*q + d;
      const int res = res_[d];
      const float sc = 0.5f*(float)(res-1);
      const float xs=(px+1.f)*sc, ys=(py+1.f)*sc, zs=(pz+1.f)*sc;
      const float fx=floorf(xs), fy=floorf(ys), fz=floorf(zs);
      const float wx=xs-fx, wy=ys-fy, wz=zs-fz;
      int ix0=min(max((int)fx,0),res-1);
      int iy0=min(max((int)fy,0),res-1);
      int iz0=min(max((int)fz,0),res-1);
      int ix1=min(ix0+1,res-1), iy1=min(iy0+1,res-1), iz1=min(iz0+1,res-1);
      const bool dense = (lvl < 3);
      unsigned X0,X1,Y0,Y1,Z0,Z1;
      if (dense){
        X0=(unsigned)ix0;            X1=(unsigned)ix1;
        Y0=(unsigned)(res*iy0);      Y1=(unsigned)(res*iy1);
        Z0=(unsigned)(res*res*iz0);  Z1=(unsigned)(res*res*iz1);
      } else {
        X0=(unsigned)ix0;                 X1=(unsigned)ix1;
        Y0=(unsigned)iy0*2654435761u;     Y1=(unsigned)iy1*2654435761u;
        Z0=(unsigned)iz0*805459861u;      Z1=(unsigned)iz1*805459861u;
      }
      const float wx0=1.f-wx, wy0=1.f-wy, wz0=1.f-wz;
      float f0=0.f, f1=0.f;
      const float2* tl = (const float2*)tab + (lvl<<14);
#pragma unroll
      for (int c = 0; c < 8; ++c){
        unsigned xc = (c&1)?X1:X0;
        unsigned yc = (c&2)?Y1:Y0;
        unsigned zc = (c&4)?Z1:Z0;
        unsigned idx = dense ? (xc+yc+zc) : ((xc^yc^zc)&16383u);
        float2 tv = tl[idx];
        float wc = ((c&1)?wx:wx0) * ((c&2)?wy:wy0) * ((c&4)?wz:wz0);
        f0 += wc*tv.x;
        f1 += wc*tv.y;
      }
      bfrag[2*d]   = (__bf16)f0;
      bfrag[2*d+1] = (__bf16)f1;
    }
    MLP_BODY(bfrag, gp)
  }
}

extern "C" void kernel_launch(void* const* d_in, const int* in_sizes, int n_in,
                              void* d_out, int out_size, void* d_ws, size_t ws_size,
                              hipStream_t stream) {
  (void)n_in; (void)out_size;
  const int nB = in_sizes[0] / 3;
  const float* xin = (const float*)d_in[0];
  const float* tab = (const float*)d_in[1];
  const float *w1=(const float*)d_in[2],  *b1=(const float*)d_in[3];
  const float *w2=(const float*)d_in[4],  *b2=(const float*)d_in[5];
  const float *w3=(const float*)d_in[6],  *b3=(const float*)d_in[7];
  const float *cw1=(const float*)d_in[8], *cb1=(const float*)d_in[9];
  const float *cw2=(const float*)d_in[10],*cb2=(const float*)d_in[11];
  const float *cw3=(const float*)d_in[12],*cb3=(const float*)d_in[13];
  const float *cw4=(const float*)d_in[14],*cb4=(const float*)d_in[15];
  float* out = (float*)d_out;

  const size_t need = (size_t)nB * 16u * 4u;
  if (ws_size >= need){
    dim3 ga((nB + CH - 1) / CH, 16);
    hash_phase<<<ga, dim3(512), 0, stream>>>(xin, tab, (unsigned int*)d_ws, nB);
    const int blocks = (nB + BLOCK - 1) / BLOCK;
    mlp_phase<<<dim3(blocks), dim3(BLOCK), 0, stream>>>(
        (const unsigned int*)d_ws, w1,b1,w2,b2,w3,b3,
        cw1,cb1,cw2,cb2,cw3,cb3,cw4,cb4, out, nB);
  } else {
    const int blocks = (nB + BLOCK - 1) / BLOCK;
    nerf_fused<<<dim3(blocks), dim3(BLOCK), 0, stream>>>(
        xin, tab, w1,b1,w2,b2,w3,b3,
        cw1,cb1,cw2,cb2,cw3,cb3,cw4,cb4, out, nB);
  }
}